// Round 7
// baseline (100.255 us; speedup 1.0000x reference)
//
#include <hip/hip_runtime.h>
#include <hip/hip_bf16.h>

// AlgebraicLinear: out[m, o] = sum_i x[m, i] * w[o, i] + bias[o]
// M = 32768, K = 256 (IN_CH), N = 256 (OUT_CH), fp32 in/out, bf16 MFMA inside.
// BM=64, 512 threads (8 waves), grid=512 -> 2 blocks/CU for cross-block overlap.

typedef __attribute__((ext_vector_type(8))) short short8;   // 8 bf16 (4 VGPRs)
typedef __attribute__((ext_vector_type(4))) short short4v;  // 4 bf16 (2 VGPRs)
typedef __attribute__((ext_vector_type(4))) float f32x4;

#define K_DIM 256
#define N_DIM 256
#define BM 64
#define THREADS 512   // 8 waves

__device__ __forceinline__ short bf16bits(float f) {
  __bf16 h = (__bf16)f;
  return __builtin_bit_cast(short, h);
}

__global__ __launch_bounds__(THREADS, 4)   // 4 waves/EU -> <=128 VGPR, 2 blocks/CU
void AlgebraicLinear_kernel(const float* __restrict__ x,
                            const float* __restrict__ w,
                            const float* __restrict__ bias,
                            float* __restrict__ out) {
  // bf16 x-tile, XOR-swizzled: (row*512 + kbyte) ^ ((row&7)<<4). 32 KiB.
  __shared__ char lds[BM * K_DIM * 2];

  const int tid  = threadIdx.x;
  const int lane = tid & 63;
  const int wid  = tid >> 6;    // wave 0..7 -> owns n-cols [wid*32, wid*32+32)
  const int g    = lane >> 4;   // 0..3 (k-group)
  const int r    = lane & 15;

  const long mbase = (long)blockIdx.x * BM;

  // ---- W -> register B-fragments (2 n-tiles x 8 k-tiles), fp32->bf16 ----
  // B-frag lane layout: B[k = kt*32 + g*8 + i][col = nt*16 + r] = W[col][k]
  short8 bfrag[2][8];
  #pragma unroll
  for (int nt = 0; nt < 2; ++nt) {
    const float* wr = w + (size_t)(wid * 32 + nt * 16 + r) * K_DIM;
    #pragma unroll
    for (int kt = 0; kt < 8; ++kt) {
      const float4* p = reinterpret_cast<const float4*>(wr + kt * 32 + g * 8);
      float4 lo = p[0];
      float4 hi = p[1];
      short8 f;
      f[0] = bf16bits(lo.x); f[1] = bf16bits(lo.y);
      f[2] = bf16bits(lo.z); f[3] = bf16bits(lo.w);
      f[4] = bf16bits(hi.x); f[5] = bf16bits(hi.y);
      f[6] = bf16bits(hi.z); f[7] = bf16bits(hi.w);
      bfrag[nt][kt] = f;
    }
  }
  const float b0 = bias[wid * 32 + r];
  const float b1 = bias[wid * 32 + 16 + r];

  // ---- stage x tile: 64 rows x 256 fp32 -> bf16 LDS (swizzled) ----
  #pragma unroll
  for (int it = 0; it < (BM * K_DIM / 4) / THREADS; ++it) {  // 8 iters
    int c   = it * THREADS + tid;
    int row = c >> 6;
    int k4  = (c & 63) * 4;
    float4 v = *reinterpret_cast<const float4*>(x + (mbase + row) * K_DIM + k4);
    short4v s;
    s[0] = bf16bits(v.x); s[1] = bf16bits(v.y);
    s[2] = bf16bits(v.z); s[3] = bf16bits(v.w);
    int addr = (row * 512 + k4 * 2) ^ ((row & 7) << 4);
    *reinterpret_cast<short4v*>(lds + addr) = s;
  }
  __syncthreads();

  // ---- compute: 4 m-tiles of 16 rows each ----
  const int ncol = wid * 32 + r;
  #pragma unroll 1
  for (int mt = 0; mt < 4; ++mt) {
    const int arow  = mt * 16 + r;
    const int abase = arow * 512;
    const int aswz  = (arow & 7) << 4;
    f32x4 acc0 = {0.f, 0.f, 0.f, 0.f};
    f32x4 acc1 = {0.f, 0.f, 0.f, 0.f};
    // A-frags in two 4-kt chunks to keep live VGPRs low (2 blocks/CU target)
    #pragma unroll
    for (int half = 0; half < 2; ++half) {
      short8 a[4];
      #pragma unroll
      for (int kk = 0; kk < 4; ++kk) {
        int kt = half * 4 + kk;
        int addr = (abase + kt * 64 + g * 16) ^ aswz;
        a[kk] = *reinterpret_cast<const short8*>(lds + addr);
      }
      #pragma unroll
      for (int kk = 0; kk < 4; ++kk) {
        acc0 = __builtin_amdgcn_mfma_f32_16x16x32_bf16(a[kk], bfrag[0][half * 4 + kk], acc0, 0, 0, 0);
        acc1 = __builtin_amdgcn_mfma_f32_16x16x32_bf16(a[kk], bfrag[1][half * 4 + kk], acc1, 0, 0, 0);
      }
    }
    // D layout: row = g*4 + rr, col = r (within tile)
    float* op = out + (mbase + mt * 16 + g * 4) * N_DIM + ncol;
    #pragma unroll
    for (int rr = 0; rr < 4; ++rr) {
      op[rr * N_DIM]      = acc0[rr] + b0;
      op[rr * N_DIM + 16] = acc1[rr] + b1;
    }
  }
}

extern "C" void kernel_launch(void* const* d_in, const int* in_sizes, int n_in,
                              void* d_out, int out_size, void* d_ws, size_t ws_size,
                              hipStream_t stream) {
  const float* x    = (const float*)d_in[0];  // (8, 4096, 256)
  const float* w    = (const float*)d_in[1];  // (256, 256)
  const float* bias = (const float*)d_in[2];  // (256,)
  float* out = (float*)d_out;                 // (8, 4096, 256)

  const int M = 8 * 4096;
  dim3 grid(M / BM);   // 512 blocks = 2 per CU
  dim3 block(THREADS); // 8 waves
  AlgebraicLinear_kernel<<<grid, block, 0, stream>>>(x, w, bias, out);
}

// Round 8
// 92.175 us; speedup vs baseline: 1.0877x; 1.0877x over previous
//
#include <hip/hip_runtime.h>
#include <hip/hip_bf16.h>

// AlgebraicLinear: out[m, o] = sum_i x[m, i] * w[o, i] + bias[o]
// M = 32768, K = 256, N = 256, fp32 in/out, bf16 MFMA inside.
// Round-8: round-5 base (BM=128, grid=256, 1 block/CU) + two-half
// double-buffered pipeline (h1 loads issued before mt0-3 compute).

typedef __attribute__((ext_vector_type(8))) short short8;   // 8 bf16
typedef __attribute__((ext_vector_type(4))) short short4v;  // 4 bf16
typedef __attribute__((ext_vector_type(4))) float f32x4;

#define K_DIM 256
#define N_DIM 256
#define BM 128
#define HALF 64
#define THREADS 512   // 8 waves

__device__ __forceinline__ short bf16bits(float f) {
  __bf16 h = (__bf16)f;
  return __builtin_bit_cast(short, h);
}

__global__ __launch_bounds__(THREADS, 2)
void AlgebraicLinear_kernel(const float* __restrict__ x,
                            const float* __restrict__ w,
                            const float* __restrict__ bias,
                            float* __restrict__ out) {
  // two 32 KiB half-tile buffers, XOR-swizzled rows of 512 B bf16
  __shared__ char lds[2 * HALF * 512];

  const int tid  = threadIdx.x;
  const int lane = tid & 63;
  const int wid  = tid >> 6;    // wave 0..7 -> n-cols [wid*32, wid*32+32)
  const int g    = lane >> 4;   // 0..3
  const int r    = lane & 15;

  const long mbase = (long)blockIdx.x * BM;

  // ---- W -> register B-fragments (loaded once per block) ----
  // B[k = kt*32 + g*8 + i][col = nt*16 + r] = W[col][k]
  short8 bfrag[2][8];
  #pragma unroll
  for (int nt = 0; nt < 2; ++nt) {
    const float* wr = w + (size_t)(wid * 32 + nt * 16 + r) * K_DIM;
    #pragma unroll
    for (int kt = 0; kt < 8; ++kt) {
      const float4* p = reinterpret_cast<const float4*>(wr + kt * 32 + g * 8);
      float4 lo = p[0];
      float4 hi = p[1];
      short8 f;
      f[0] = bf16bits(lo.x); f[1] = bf16bits(lo.y);
      f[2] = bf16bits(lo.z); f[3] = bf16bits(lo.w);
      f[4] = bf16bits(hi.x); f[5] = bf16bits(hi.y);
      f[6] = bf16bits(hi.z); f[7] = bf16bits(hi.w);
      bfrag[nt][kt] = f;
    }
  }
  const float b0 = bias[wid * 32 + r];
  const float b1 = bias[wid * 32 + 16 + r];

  // ---- stage half 0 (rows 0..63): load -> cvt -> LDS buf0 ----
  // per it: wave wid stages row it*8+wid; lane covers bytes lane*8..+7
  #pragma unroll
  for (int it = 0; it < 8; ++it) {
    int row = it * 8 + wid;
    float4 v = *reinterpret_cast<const float4*>(x + (mbase + row) * K_DIM + lane * 4);
    short4v s;
    s[0] = bf16bits(v.x); s[1] = bf16bits(v.y);
    s[2] = bf16bits(v.z); s[3] = bf16bits(v.w);
    int addr = (row * 512 + lane * 8) ^ ((row & 7) << 4);
    *reinterpret_cast<short4v*>(lds + addr) = s;
  }
  __syncthreads();

  // ---- issue half-1 global loads (held in regs; overlap with compute) ----
  float4 v1[8];
  #pragma unroll
  for (int it = 0; it < 8; ++it) {
    int row = HALF + it * 8 + wid;
    v1[it] = *reinterpret_cast<const float4*>(x + (mbase + row) * K_DIM + lane * 4);
  }

  // ---- compute m-tiles 0..3 from buf0, accs kept in registers ----
  f32x4 acc[4][2];
  #pragma unroll
  for (int mt = 0; mt < 4; ++mt) {
    const int lr   = mt * 16 + r;
    const int base = lr * 512;
    const int swz  = (lr & 7) << 4;
    short8 a[8];
    #pragma unroll
    for (int kt = 0; kt < 8; ++kt)
      a[kt] = *reinterpret_cast<const short8*>(lds + ((base + kt * 64 + g * 16) ^ swz));
    f32x4 c0 = {0.f, 0.f, 0.f, 0.f};
    f32x4 c1 = {0.f, 0.f, 0.f, 0.f};
    #pragma unroll
    for (int kt = 0; kt < 8; ++kt) {
      c0 = __builtin_amdgcn_mfma_f32_16x16x32_bf16(a[kt], bfrag[0][kt], c0, 0, 0, 0);
      c1 = __builtin_amdgcn_mfma_f32_16x16x32_bf16(a[kt], bfrag[1][kt], c1, 0, 0, 0);
    }
    acc[mt][0] = c0;
    acc[mt][1] = c1;
  }

  // ---- cvt + write half 1 into buf1 (vmcnt waits land here) ----
  #pragma unroll
  for (int it = 0; it < 8; ++it) {
    int lr = it * 8 + wid;
    short4v s;
    s[0] = bf16bits(v1[it].x); s[1] = bf16bits(v1[it].y);
    s[2] = bf16bits(v1[it].z); s[3] = bf16bits(v1[it].w);
    int addr = HALF * 512 + ((lr * 512 + lane * 8) ^ ((lr & 7) << 4));
    *reinterpret_cast<short4v*>(lds + addr) = s;
  }
  __syncthreads();

  // ---- store m-tiles 0..3 (overlaps mt4..7 ds_read/MFMA below) ----
  const int ncol = wid * 32 + r;
  #pragma unroll
  for (int mt = 0; mt < 4; ++mt) {
    float* op = out + (mbase + mt * 16 + g * 4) * N_DIM + ncol;
    #pragma unroll
    for (int rr = 0; rr < 4; ++rr) {
      op[rr * N_DIM]      = acc[mt][0][rr] + b0;
      op[rr * N_DIM + 16] = acc[mt][1][rr] + b1;
    }
  }

  // ---- compute + store m-tiles 4..7 from buf1 ----
  #pragma unroll
  for (int mt = 0; mt < 4; ++mt) {
    const int lr   = mt * 16 + r;
    const int base = HALF * 512 + lr * 512;
    const int swz  = (lr & 7) << 4;
    short8 a[8];
    #pragma unroll
    for (int kt = 0; kt < 8; ++kt)
      a[kt] = *reinterpret_cast<const short8*>(lds + (((lr * 512 + kt * 64 + g * 16) ^ swz) + HALF * 512));
    f32x4 c0 = {0.f, 0.f, 0.f, 0.f};
    f32x4 c1 = {0.f, 0.f, 0.f, 0.f};
    #pragma unroll
    for (int kt = 0; kt < 8; ++kt) {
      c0 = __builtin_amdgcn_mfma_f32_16x16x32_bf16(a[kt], bfrag[0][kt], c0, 0, 0, 0);
      c1 = __builtin_amdgcn_mfma_f32_16x16x32_bf16(a[kt], bfrag[1][kt], c1, 0, 0, 0);
    }
    float* op = out + (mbase + (mt + 4) * 16 + g * 4) * N_DIM + ncol;
    #pragma unroll
    for (int rr = 0; rr < 4; ++rr) {
      op[rr * N_DIM]      = c0[rr] + b0;
      op[rr * N_DIM + 16] = c1[rr] + b1;
    }
  }
}

extern "C" void kernel_launch(void* const* d_in, const int* in_sizes, int n_in,
                              void* d_out, int out_size, void* d_ws, size_t ws_size,
                              hipStream_t stream) {
  const float* x    = (const float*)d_in[0];  // (8, 4096, 256)
  const float* w    = (const float*)d_in[1];  // (256, 256)
  const float* bias = (const float*)d_in[2];  // (256,)
  float* out = (float*)d_out;                 // (8, 4096, 256)

  const int M = 8 * 4096;
  dim3 grid(M / BM);   // 256 blocks = 1 per CU
  dim3 block(THREADS); // 8 waves
  AlgebraicLinear_kernel<<<grid, block, 0, stream>>>(x, w, bias, out);
}